// Round 3
// baseline (7376.142 us; speedup 1.0000x reference)
//
#include <hip/hip_runtime.h>
#include <math.h>

#define B_ 2
#define L_ 160000
#define H_ 128
#define N_ 64
#define NL_ 4
#define LMAX_ 1024
#define TS_ 1001
#define MR_ 16
#define CLS_ 88
#define REP_ 16016

#define CH_ 16000             // l-chunk (10 chunks per layer)
#define NCH_ 10
#define CT_ 4096              // conv time tile (4 tiles per chunk, last partial)
#define US(q) us[(q) + ((q) >> 5)]   // pad-every-32 swizzle

typedef unsigned short ushort_t;
typedef unsigned int uint_t;

__device__ __forceinline__ float bf2f(ushort_t h) {
  uint_t u = ((uint_t)h) << 16;
  return __uint_as_float(u);
}
__device__ __forceinline__ ushort_t f2bf(float f) {
  uint_t u = __float_as_uint(f);
  uint_t r = (u + 0x7fffu + ((u >> 16) & 1u)) >> 16;
  return (ushort_t)r;
}

// ---------------- encoder ----------------
__global__ __launch_bounds__(256) void k_encode(const float* __restrict__ x,
                                                const float* __restrict__ enc_w,
                                                const float* __restrict__ enc_b,
                                                float* __restrict__ u) {
  int idx = blockIdx.x * 256 + threadIdx.x;
  int idx4 = idx * 4;
  int b = idx4 / (H_ * L_);
  int rem = idx4 - b * (H_ * L_);
  int h = rem / L_;
  int l = rem - h * L_;
  float w = enc_w[h], bb = enc_b[h];
  float4 xv = *(const float4*)(x + b * L_ + l);
  float4 o = make_float4(xv.x * w + bb, xv.y * w + bb, xv.z * w + bb, xv.w * w + bb);
  *(float4*)(u + (long long)(b * H_ + h) * L_ + l) = o;
}

// ---------------- discretization ----------------
__global__ __launch_bounds__(256) void k_ct(const float* __restrict__ log_dt,
                                            const float* __restrict__ log_A_real,
                                            const float* __restrict__ A_imag,
                                            const float* __restrict__ C_re,
                                            const float* __restrict__ C_im,
                                            float* __restrict__ ct) {
  int idx = blockIdx.x * 256 + threadIdx.x;
  if (idx >= NL_ * H_ * N_) return;
  int h = (idx / N_) % H_;
  int i = idx / (N_ * H_);
  float dt = expf(log_dt[i * H_ + h]);
  float are = -expf(log_A_real[idx]);
  float aim = A_imag[idx];
  float dr = are * dt, di = aim * dt;
  float e = expf(dr);
  float si, co;
  sincosf(di, &si, &co);
  float er = e * co - 1.0f;
  float ei = e * si;
  float den = are * are + aim * aim;
  float qr = (er * are + ei * aim) / den;
  float qi = (ei * are - er * aim) / den;
  float cr = C_re[idx], cim = C_im[idx];
  ct[idx * 4 + 0] = dr;
  ct[idx * 4 + 1] = di;
  ct[idx * 4 + 2] = cr * qr - cim * qi;
  ct[idx * 4 + 3] = cr * qi + cim * qr;
}

// ---------------- K[h,l] ----------------
__global__ __launch_bounds__(256) void k_kern(const float* __restrict__ ct,
                                              float* __restrict__ Kb) {
  int ih = blockIdx.x;
  __shared__ float4 cs[N_];
  if (threadIdx.x < N_) cs[threadIdx.x] = ((const float4*)ct)[ih * N_ + threadIdx.x];
  __syncthreads();
  for (int l = threadIdx.x; l < LMAX_; l += 256) {
    float fl = (float)l;
    float s = 0.f;
    #pragma unroll 4
    for (int n = 0; n < N_; n++) {
      float4 q = cs[n];
      float e = expf(q.x * fl);
      float si, co;
      sincosf(q.y * fl, &si, &co);
      s += e * (q.z * co - q.w * si);
    }
    Kb[ih * LMAX_ + l] = 2.f * s;
  }
}

// ---------------- conv + skip + GELU -> bf16 y (chunk-local) ----------------
__global__ __launch_bounds__(256) void k_conv(const float* __restrict__ u,
                                              const float* __restrict__ stash,
                                              const float* __restrict__ Kb,
                                              const float* __restrict__ Dv,
                                              ushort_t* __restrict__ y,
                                              int layer, int c) {
  int tile = blockIdx.x & 3;
  int bh = blockIdx.x >> 2;
  int h = bh & (H_ - 1);
  int t0 = tile * CT_;                          // chunk-local col of tile start
  __shared__ float us[(CT_ + LMAX_) + ((CT_ + LMAX_) >> 5)];
  __shared__ float ks[LMAX_];
  const float* ubh = u + (long long)bh * L_;
  for (int q = threadIdx.x; q < CT_ + LMAX_; q += 256) {
    int gl = t0 - LMAX_ + q;                    // chunk-local
    float v;
    if (gl < 0) {
      v = (c > 0) ? stash[bh * LMAX_ + (gl + LMAX_)] : 0.f;
    } else {
      long long g = (long long)c * CH_ + gl;
      v = (g < L_) ? ubh[g] : 0.f;
    }
    US(q) = v;
  }
  for (int q = threadIdx.x; q < LMAX_; q += 256)
    ks[q] = Kb[(layer * H_ + h) * LMAX_ + q];
  __syncthreads();

  float acc[16];
  #pragma unroll
  for (int j = 0; j < 16; j++) acc[j] = 0.f;
  int tb = threadIdx.x * 16;

  float W[23];
  {
    int s = LMAX_ - 7 + tb;
    #pragma unroll
    for (int m = 0; m < 23; m++) { int q = s + m; W[m] = US(q); }
  }
  for (int l0 = 0; l0 < LMAX_; l0 += 8) {
    if (l0 > 0) {
      #pragma unroll
      for (int m = 22; m >= 8; m--) W[m] = W[m - 8];
      int s = LMAX_ - l0 - 7 + tb;
      #pragma unroll
      for (int m = 0; m < 8; m++) { int q = s + m; W[m] = US(q); }
    }
    float k0[8];
    #pragma unroll
    for (int d = 0; d < 8; d++) k0[d] = ks[l0 + d];
    #pragma unroll
    for (int d = 0; d < 8; d++) {
      #pragma unroll
      for (int j = 0; j < 16; j++)
        acc[j] = fmaf(k0[d], W[j - d + 7], acc[j]);
    }
  }
  float Dh = Dv[layer * H_ + h];
  #pragma unroll
  for (int j = 0; j < 16; j++) {
    int q = LMAX_ + tb + j;
    float v = acc[j] + Dh * US(q);
    float t = tanhf(0.7978845608028654f * (v + 0.044715f * v * v * v));
    acc[j] = 0.5f * v * (1.f + t);
  }
  int tg = t0 + tb;                             // chunk-local output col
  if (tg + 16 <= CH_) {
    union { ushort_t s[16]; uint4 v[2]; } tmp;
    #pragma unroll
    for (int j = 0; j < 16; j++) tmp.s[j] = f2bf(acc[j]);
    ushort_t* yp = y + (long long)bh * CH_ + tg;
    *(uint4*)yp = tmp.v[0];
    *(uint4*)(yp + 8) = tmp.v[1];
  }
}

// ---------------- z = out_w @ y + out_b (128x128 tile, BK=32) ----------------
__global__ __launch_bounds__(256) void k_gemm(const ushort_t* __restrict__ y,
                                              const float* __restrict__ Wt,
                                              const float* __restrict__ bias,
                                              float* __restrict__ z) {
  __shared__ float Ws[32 * 132];
  __shared__ float Ys[32 * 132];
  int lblk = blockIdx.x, pblk = blockIdx.y, b = blockIdx.z;
  int p0 = pblk * 128;
  int lc0 = lblk * 128;
  const ushort_t* yb = y + (long long)b * H_ * CH_;
  int tx = threadIdx.x & 15, ty = threadIdx.x >> 4;
  float acc[8][8];
  #pragma unroll
  for (int i = 0; i < 8; i++)
    #pragma unroll
    for (int j = 0; j < 8; j++) acc[i][j] = 0.f;

  for (int kk0 = 0; kk0 < 128; kk0 += 32) {
    __syncthreads();
    for (int i = threadIdx.x; i < 32 * 128; i += 256) {
      int k = i & 31, p = i >> 5;
      Ws[k * 132 + p] = Wt[(p0 + p) * 128 + kk0 + k];
    }
    for (int i = threadIdx.x; i < 32 * 16; i += 256) {
      int k = i >> 4, seg = i & 15;
      uint4 v = *(const uint4*)(yb + (long long)(kk0 + k) * CH_ + lc0 + seg * 8);
      const ushort_t* hp = (const ushort_t*)&v;
      float* dst = Ys + k * 132 + seg * 8;
      #pragma unroll
      for (int e = 0; e < 8; e++) dst[e] = bf2f(hp[e]);
    }
    __syncthreads();
    #pragma unroll 2
    for (int k = 0; k < 32; k++) {
      float4 w0 = *(const float4*)(Ws + k * 132 + ty * 8);
      float4 w1 = *(const float4*)(Ws + k * 132 + ty * 8 + 4);
      float4 a0 = *(const float4*)(Ys + k * 132 + tx * 8);
      float4 a1 = *(const float4*)(Ys + k * 132 + tx * 8 + 4);
      float wv[8] = {w0.x, w0.y, w0.z, w0.w, w1.x, w1.y, w1.z, w1.w};
      float yv[8] = {a0.x, a0.y, a0.z, a0.w, a1.x, a1.y, a1.z, a1.w};
      #pragma unroll
      for (int i = 0; i < 8; i++)
        #pragma unroll
        for (int j = 0; j < 8; j++)
          acc[i][j] = fmaf(wv[i], yv[j], acc[i][j]);
    }
  }
  #pragma unroll
  for (int i = 0; i < 8; i++) {
    int p = p0 + ty * 8 + i;
    float bv = bias[p];
    float* zp = z + (long long)(b * 256 + p) * CH_ + lc0 + tx * 8;
    *(float4*)zp = make_float4(acc[i][0] + bv, acc[i][1] + bv, acc[i][2] + bv, acc[i][3] + bv);
    *(float4*)(zp + 4) = make_float4(acc[i][4] + bv, acc[i][5] + bv, acc[i][6] + bv, acc[i][7] + bv);
  }
}

// ---------------- GLU + residual + LN, in-place u update + stash save ----------------
__global__ __launch_bounds__(256) void k_glu_ln(const float* __restrict__ z,
                                                float* __restrict__ u,
                                                float* __restrict__ stash,
                                                const float* __restrict__ lng,
                                                const float* __restrict__ lnb,
                                                int c) {
  __shared__ float zs[256][33];
  __shared__ float usm[128][33];
  int lblk = blockIdx.x, b = blockIdx.y;
  int lc0 = lblk * 32;                           // chunk-local
  long long l0g = (long long)c * CH_ + lc0;      // global
  for (int i = threadIdx.x; i < 256 * 32; i += 256) {
    int p = i >> 5, l = i & 31;
    zs[p][l] = z[(long long)(b * 256 + p) * CH_ + lc0 + l];
  }
  for (int i = threadIdx.x; i < 128 * 32; i += 256) {
    int hh = i >> 5, l = i & 31;
    usm[hh][l] = u[(long long)(b * H_ + hh) * L_ + l0g + l];
  }
  __syncthreads();
  // save old-u tail for next chunk's conv lookback
  if (lc0 >= CH_ - LMAX_ && c < NCH_ - 1) {
    int so = lc0 - (CH_ - LMAX_);
    for (int i = threadIdx.x; i < 128 * 32; i += 256) {
      int hh = i >> 5, l = i & 31;
      stash[(b * H_ + hh) * LMAX_ + so + l] = usm[hh][l];
    }
  }
  __syncthreads();
  int lane = threadIdx.x & 63, w = threadIdx.x >> 6;
  float g0 = lng[lane], g1 = lng[lane + 64];
  float bb0 = lnb[lane], bb1 = lnb[lane + 64];
  for (int l = w * 8; l < w * 8 + 8; l++) {
    float a0 = zs[lane][l], a1 = zs[lane + 64][l];
    float s0 = zs[lane + 128][l], s1 = zs[lane + 192][l];
    float v0 = a0 * (1.f / (1.f + expf(-s0))) + usm[lane][l];
    float v1 = a1 * (1.f / (1.f + expf(-s1))) + usm[lane + 64][l];
    float sum = v0 + v1, sq = v0 * v0 + v1 * v1;
    #pragma unroll
    for (int m = 1; m < 64; m <<= 1) {
      sum += __shfl_xor(sum, m);
      sq += __shfl_xor(sq, m);
    }
    float mean = sum * (1.f / 128.f);
    float var = sq * (1.f / 128.f) - mean * mean;
    float rstd = rsqrtf(var + 1e-5f);
    usm[lane][l] = (v0 - mean) * rstd * g0 + bb0;
    usm[lane + 64][l] = (v1 - mean) * rstd * g1 + bb1;
  }
  __syncthreads();
  for (int i = threadIdx.x; i < 128 * 32; i += 256) {
    int hh = i >> 5, l = i & 31;
    u[(long long)(b * H_ + hh) * L_ + l0g + l] = usm[hh][l];
  }
}

// ---------------- mean pool ----------------
__global__ __launch_bounds__(256) void k_pool(const float* __restrict__ u,
                                              float* __restrict__ feat) {
  int bh = blockIdx.x;
  const float4* p = (const float4*)(u + (long long)bh * L_);
  float s = 0.f;
  for (int i = threadIdx.x; i < L_ / 4; i += 256) {
    float4 v = p[i];
    s += v.x + v.y + v.z + v.w;
  }
  __shared__ float smv[256];
  smv[threadIdx.x] = s;
  __syncthreads();
  for (int st = 128; st > 0; st >>= 1) {
    if (threadIdx.x < st) smv[threadIdx.x] += smv[threadIdx.x + st];
    __syncthreads();
  }
  if (threadIdx.x == 0) feat[bh] = smv[0] * (1.f / L_);
}

// ---------------- decoder ----------------
__global__ __launch_bounds__(256) void k_dec(const float* __restrict__ feat,
                                             const float* __restrict__ dw,
                                             const float* __restrict__ db,
                                             float* __restrict__ rep) {
  int idx = blockIdx.x * 256 + threadIdx.x;
  if (idx >= B_ * REP_) return;
  int b = idx / REP_, r = idx - b * REP_;
  float s = db[r];
  #pragma unroll 8
  for (int h = 0; h < H_; h++) s = fmaf(feat[b * H_ + h], dw[h * REP_ + r], s);
  rep[idx] = s;
}

// ---------------- heads ----------------
__global__ __launch_bounds__(256) void k_head(const float* __restrict__ rep,
                                              const float* __restrict__ hw,
                                              const float* __restrict__ hb,
                                              float* __restrict__ out) {
  int idx = blockIdx.x * 256 + threadIdx.x;
  if (idx >= 4 * B_ * TS_ * CLS_) return;
  int c = idx % CLS_;
  int t = (idx / CLS_) % TS_;
  int b = (idx / (CLS_ * TS_)) % B_;
  int k = idx / (CLS_ * TS_ * B_);
  float s = hb[k * CLS_ + c];
  const float* rp = rep + ((long long)b * TS_ + t) * MR_;
  #pragma unroll
  for (int m = 0; m < MR_; m++) s = fmaf(rp[m], hw[(k * MR_ + m) * CLS_ + c], s);
  out[idx] = s;
}

extern "C" void kernel_launch(void* const* d_in, const int* in_sizes, int n_in,
                              void* d_out, int out_size, void* d_ws, size_t ws_size,
                              hipStream_t stream) {
  const float* x = (const float*)d_in[0];
  const float* enc_w = (const float*)d_in[1];
  const float* enc_b = (const float*)d_in[2];
  const float* log_dt = (const float*)d_in[3];
  const float* log_A_real = (const float*)d_in[4];
  const float* A_imag = (const float*)d_in[5];
  const float* C_re = (const float*)d_in[6];
  const float* C_im = (const float*)d_in[7];
  const float* Dv = (const float*)d_in[8];
  const float* out_w = (const float*)d_in[9];
  const float* out_b = (const float*)d_in[10];
  const float* ln_g = (const float*)d_in[11];
  const float* ln_b = (const float*)d_in[12];
  const float* dec_w = (const float*)d_in[13];
  const float* dec_b = (const float*)d_in[14];
  const float* head_w = (const float*)d_in[15];
  const float* head_b = (const float*)d_in[16];

  // Workspace layout (floats):
  //   u     : 40,960,000            (163.8 MB, fp32 residual stream)
  //   y     : 2,048,000 f32-slots   (8.2 MB, bf16 chunk of conv output)
  //   z     : 8,192,000             (32.8 MB, fp32 chunk of GEMM output)
  //   stash : 262,144               (1.0 MB, old-u tail for conv lookback)
  //   Kb    : 524,288  ct: 131,072  feat: 256  rep: 32,032
  // total ~208.6 MB — guard below protects against a smaller ws_size.
  if (ws_size < 210000000ULL) return;   // diagnostic: clean fail instead of fault

  float* ws = (float*)d_ws;
  float* u = ws;
  ushort_t* y = (ushort_t*)(ws + 40960000);
  float* z = ws + 40960000 + 2048000;
  float* stash = z + 8192000;
  float* Kb = stash + 262144;
  float* ct = Kb + 524288;
  float* feat = ct + 131072;
  float* rep = feat + 256;

  k_encode<<<(B_ * H_ * L_ / 4 + 255) / 256, 256, 0, stream>>>(x, enc_w, enc_b, u);
  k_ct<<<(NL_ * H_ * N_ + 255) / 256, 256, 0, stream>>>(log_dt, log_A_real, A_imag,
                                                        C_re, C_im, ct);
  k_kern<<<NL_ * H_, 256, 0, stream>>>(ct, Kb);

  for (int i = 0; i < NL_; i++) {
    for (int c = 0; c < NCH_; c++) {
      k_conv<<<B_ * H_ * 4, 256, 0, stream>>>(u, stash, Kb, Dv, y, i, c);
      k_gemm<<<dim3(CH_ / 128, 2, B_), 256, 0, stream>>>(
          y, out_w + i * 256 * 128, out_b + i * 256, z);
      k_glu_ln<<<dim3(CH_ / 32, B_), 256, 0, stream>>>(z, u, stash, ln_g + i * H_,
                                                       ln_b + i * H_, c);
    }
  }
  k_pool<<<B_ * H_, 256, 0, stream>>>(u, feat);
  k_dec<<<(B_ * REP_ + 255) / 256, 256, 0, stream>>>(feat, dec_w, dec_b, rep);
  k_head<<<(4 * B_ * TS_ * CLS_ + 255) / 256, 256, 0, stream>>>(rep, head_w, head_b,
                                                               (float*)d_out);
}

// Round 4
// 3834.094 us; speedup vs baseline: 1.9238x; 1.9238x over previous
//
#include <hip/hip_runtime.h>
#include <math.h>

#define B_ 2
#define L_ 160000
#define H_ 128
#define N_ 64
#define NL_ 4
#define LMAX_ 1024
#define TS_ 1001
#define MR_ 16
#define CLS_ 88
#define REP_ 16016

#define CH_ 16000             // l-chunk (10 chunks per layer)
#define NCH_ 10
#define NJ_ 40                // tap blocks per tile: j in [-8, 31]
#define WIN_ 3208             // reversed-window elements per phase copy (mult of 8, WIN/4 odd)
#define OUTB_ 2048            // outputs per conv block (4 waves x 2 tiles x 256)
#define KE_STRIDE_ 1536       // Ke entries per (layer,h): d in [-256, 1280)

typedef unsigned short ushort_t;
typedef unsigned int uint_t;
typedef short bf16x8 __attribute__((ext_vector_type(8)));
typedef float f32x4 __attribute__((ext_vector_type(4)));

__device__ __forceinline__ float bf2f(ushort_t h) {
  uint_t u = ((uint_t)h) << 16;
  return __uint_as_float(u);
}
__device__ __forceinline__ ushort_t f2bf(float f) {
  uint_t u = __float_as_uint(f);
  uint_t r = (u + 0x7fffu + ((u >> 16) & 1u)) >> 16;
  return (ushort_t)r;
}

// ---------------- encoder ----------------
__global__ __launch_bounds__(256) void k_encode(const float* __restrict__ x,
                                                const float* __restrict__ enc_w,
                                                const float* __restrict__ enc_b,
                                                float* __restrict__ u) {
  int idx = blockIdx.x * 256 + threadIdx.x;
  int idx4 = idx * 4;
  int b = idx4 / (H_ * L_);
  int rem = idx4 - b * (H_ * L_);
  int h = rem / L_;
  int l = rem - h * L_;
  float w = enc_w[h], bb = enc_b[h];
  float4 xv = *(const float4*)(x + b * L_ + l);
  float4 o = make_float4(xv.x * w + bb, xv.y * w + bb, xv.z * w + bb, xv.w * w + bb);
  *(float4*)(u + (long long)(b * H_ + h) * L_ + l) = o;
}

// ---------------- discretization ----------------
__global__ __launch_bounds__(256) void k_ct(const float* __restrict__ log_dt,
                                            const float* __restrict__ log_A_real,
                                            const float* __restrict__ A_imag,
                                            const float* __restrict__ C_re,
                                            const float* __restrict__ C_im,
                                            float* __restrict__ ct) {
  int idx = blockIdx.x * 256 + threadIdx.x;
  if (idx >= NL_ * H_ * N_) return;
  int h = (idx / N_) % H_;
  int i = idx / (N_ * H_);
  float dt = expf(log_dt[i * H_ + h]);
  float are = -expf(log_A_real[idx]);
  float aim = A_imag[idx];
  float dr = are * dt, di = aim * dt;
  float e = expf(dr);
  float si, co;
  sincosf(di, &si, &co);
  float er = e * co - 1.0f;
  float ei = e * si;
  float den = are * are + aim * aim;
  float qr = (er * are + ei * aim) / den;
  float qi = (ei * are - er * aim) / den;
  float cr = C_re[idx], cim = C_im[idx];
  ct[idx * 4 + 0] = dr;
  ct[idx * 4 + 1] = di;
  ct[idx * 4 + 2] = cr * qr - cim * qi;
  ct[idx * 4 + 3] = cr * qi + cim * qr;
}

// ---------------- Ke[layer,h, s] bf16, s=d+256, zero outside [0,1024) ----------------
__global__ __launch_bounds__(256) void k_ke(const float* __restrict__ ct,
                                            ushort_t* __restrict__ Ke) {
  int ih = blockIdx.x;                          // NL*H
  __shared__ float4 cs[N_];
  if (threadIdx.x < N_) cs[threadIdx.x] = ((const float4*)ct)[ih * N_ + threadIdx.x];
  __syncthreads();
  for (int s = threadIdx.x; s < KE_STRIDE_; s += 256) {
    int d = s - 256;
    float val = 0.f;
    if (d >= 0 && d < LMAX_) {
      float fl = (float)d;
      float acc = 0.f;
      #pragma unroll 4
      for (int n = 0; n < N_; n++) {
        float4 q = cs[n];
        float e = expf(q.x * fl);
        float si, co;
        sincosf(q.y * fl, &si, &co);
        acc += e * (q.z * co - q.w * si);
      }
      val = 2.f * acc;
    }
    Ke[(size_t)ih * KE_STRIDE_ + s] = f2bf(val);
  }
}

// ---------------- MFMA conv + skip + GELU -> bf16 y (chunk-local) ----------------
// Block: 4 waves, 2048 outputs (8 tiles of 256). Wave w: tiles O0+512w, O0+512w+256.
// LDS: reversed window R[t] = u[Gmax - t], 4 phase-shifted copies for aligned b64 reads.
__global__ __launch_bounds__(256) void k_conv_mfma(const float* __restrict__ u,
                                                   const float* __restrict__ stash,
                                                   const ushort_t* __restrict__ Ke,
                                                   const float* __restrict__ Dv,
                                                   ushort_t* __restrict__ y,
                                                   int layer, int c) {
  int sub = blockIdx.x & 7;                    // 8 sub-chunks of 2048 (last partial-valid)
  int bh = blockIdx.x >> 3;
  int h = bh & (H_ - 1);
  int O0 = sub * OUTB_;
  int Gmax = O0 + 2063;                        // chunk-local u-index of R[0]
  __shared__ ushort_t win[4 * WIN_];           // 25664 B
  int tid = threadIdx.x;
  int lane = tid & 63, w = tid >> 6;
  int m = lane & 15, g = lane >> 4;

  // ---- K fragments: 40 x 16B global loads (tile-invariant, stays in VGPRs) ----
  const ushort_t* keh = Ke + (size_t)(layer * H_ + h) * KE_STRIDE_ + 256;
  bf16x8 Kf[NJ_];
  #pragma unroll
  for (int jjj = 0; jjj < NJ_; jjj++) {
    Kf[jjj] = *(const bf16x8*)(keh + 16 * m + 8 * g + 32 * jjj - 256);
  }

  // ---- stage reversed window, 4 phase copies ----
  const float* ubh = u + (size_t)bh * L_;
  const float* sbh = stash + bh * LMAX_;
  for (int T = tid; T < WIN_ / 8; T += 256) {
    int topt = Gmax - 8 * T;                   // loads R[8T..8T+16) = u[topt-15 .. topt]
    ushort_t vb[16];
    if (topt - 15 >= 0 && (long long)c * CH_ + topt < L_) {
      const float4* fp = (const float4*)(ubh + (long long)c * CH_ + topt - 15);
      float4 q0 = fp[0], q1 = fp[1], q2 = fp[2], q3 = fp[3];
      float tmp[16] = {q0.x, q0.y, q0.z, q0.w, q1.x, q1.y, q1.z, q1.w,
                       q2.x, q2.y, q2.z, q2.w, q3.x, q3.y, q3.z, q3.w};
      #pragma unroll
      for (int d = 0; d < 16; d++) vb[d] = f2bf(tmp[15 - d]);
    } else {
      #pragma unroll
      for (int d = 0; d < 16; d++) {
        int gl = topt - d;
        float v = 0.f;
        if (gl >= 0) {
          long long gg = (long long)c * CH_ + gl;
          if (gg < L_) v = ubh[gg];
        } else if (gl >= -LMAX_ && c > 0) {
          v = sbh[LMAX_ + gl];
        }
        vb[d] = f2bf(v);
      }
    }
    #pragma unroll
    for (int p = 0; p < 4; p++) {
      union { bf16x8 v; ushort_t s[8]; } gr;
      #pragma unroll
      for (int e = 0; e < 8; e++) gr.s[e] = vb[p + e];
      *(bf16x8*)((char*)win + p * (2 * WIN_) + 16 * T) = gr.v;
    }
  }
  __syncthreads();

  // ---- main loop: 2 tiles interleaved, 40 MFMAs each ----
  const char* wb = (const char*)win;
  int l0A = O0 + (w << 9);
  f32x4 accA = {0.f, 0.f, 0.f, 0.f}, accB = {0.f, 0.f, 0.f, 0.f};
  int t0 = Gmax - l0A - m + 8 * g - 256;       // tile A, jjj=0
  #pragma unroll
  for (int jjj = 0; jjj < NJ_; jjj++) {
    int tA = t0 + (jjj << 5);
    int pA = tA & 3;
    const char* baseA = wb + pA * (2 * WIN_) + 2 * (tA - pA);
    union { bf16x8 v; short4 h[2]; } fa, fb;
    fa.h[0] = *(const short4*)baseA;
    fa.h[1] = *(const short4*)(baseA + 8);
    accA = __builtin_amdgcn_mfma_f32_16x16x32_bf16(fa.v, Kf[jjj], accA, 0, 0, 0);
    const char* baseB = baseA - 512;           // tile B = tile A + 256 outputs
    fb.h[0] = *(const short4*)baseB;
    fb.h[1] = *(const short4*)(baseB + 8);
    accB = __builtin_amdgcn_mfma_f32_16x16x32_bf16(fb.v, Kf[jjj], accB, 0, 0, 0);
  }

  // ---- epilogue: skip + GELU + bf16 store, per tile ----
  float Dh = Dv[layer * H_ + h];
  ushort_t* ybh = y + (size_t)bh * CH_;
  #pragma unroll
  for (int tile = 0; tile < 2; tile++) {
    f32x4 acc = tile ? accB : accA;
    int l0 = l0A + tile * 256;
    int outb = l0 + 16 * m + 4 * g;            // r=0 output (chunk-local)
    int tu = Gmax - outb - 3;
    int pu = tu & 3;
    union { short4 s4; ushort_t us[4]; } uu;
    uu.s4 = *(const short4*)(wb + pu * (2 * WIN_) + 2 * (tu - pu));  // u[outb+3-e]
    union { ushort_t s[4]; short4 v; } pk;
    #pragma unroll
    for (int r = 0; r < 4; r++) {
      float uval = bf2f(uu.us[3 - r]);
      float v = acc[r] + Dh * uval;
      float t = tanhf(0.7978845608028654f * (v + 0.044715f * v * v * v));
      pk.s[r] = f2bf(0.5f * v * (1.f + t));
    }
    if (outb < CH_) *(short4*)(ybh + outb) = pk.v;
  }
}

// ---------------- z = out_w @ y + out_b (128x128 tile, BK=32) ----------------
__global__ __launch_bounds__(256) void k_gemm(const ushort_t* __restrict__ y,
                                              const float* __restrict__ Wt,
                                              const float* __restrict__ bias,
                                              float* __restrict__ z) {
  __shared__ float Ws[32 * 132];
  __shared__ float Ys[32 * 132];
  int lblk = blockIdx.x, pblk = blockIdx.y, b = blockIdx.z;
  int p0 = pblk * 128;
  int lc0 = lblk * 128;
  const ushort_t* yb = y + (long long)b * H_ * CH_;
  int tx = threadIdx.x & 15, ty = threadIdx.x >> 4;
  float acc[8][8];
  #pragma unroll
  for (int i = 0; i < 8; i++)
    #pragma unroll
    for (int j = 0; j < 8; j++) acc[i][j] = 0.f;

  for (int kk0 = 0; kk0 < 128; kk0 += 32) {
    __syncthreads();
    for (int i = threadIdx.x; i < 32 * 128; i += 256) {
      int k = i & 31, p = i >> 5;
      Ws[k * 132 + p] = Wt[(p0 + p) * 128 + kk0 + k];
    }
    for (int i = threadIdx.x; i < 32 * 16; i += 256) {
      int k = i >> 4, seg = i & 15;
      uint4 v = *(const uint4*)(yb + (long long)(kk0 + k) * CH_ + lc0 + seg * 8);
      const ushort_t* hp = (const ushort_t*)&v;
      float* dst = Ys + k * 132 + seg * 8;
      #pragma unroll
      for (int e = 0; e < 8; e++) dst[e] = bf2f(hp[e]);
    }
    __syncthreads();
    #pragma unroll 2
    for (int k = 0; k < 32; k++) {
      float4 w0 = *(const float4*)(Ws + k * 132 + ty * 8);
      float4 w1 = *(const float4*)(Ws + k * 132 + ty * 8 + 4);
      float4 a0 = *(const float4*)(Ys + k * 132 + tx * 8);
      float4 a1 = *(const float4*)(Ys + k * 132 + tx * 8 + 4);
      float wv[8] = {w0.x, w0.y, w0.z, w0.w, w1.x, w1.y, w1.z, w1.w};
      float yv[8] = {a0.x, a0.y, a0.z, a0.w, a1.x, a1.y, a1.z, a1.w};
      #pragma unroll
      for (int i = 0; i < 8; i++)
        #pragma unroll
        for (int j = 0; j < 8; j++)
          acc[i][j] = fmaf(wv[i], yv[j], acc[i][j]);
    }
  }
  #pragma unroll
  for (int i = 0; i < 8; i++) {
    int p = p0 + ty * 8 + i;
    float bv = bias[p];
    float* zp = z + (long long)(b * 256 + p) * CH_ + lc0 + tx * 8;
    *(float4*)zp = make_float4(acc[i][0] + bv, acc[i][1] + bv, acc[i][2] + bv, acc[i][3] + bv);
    *(float4*)(zp + 4) = make_float4(acc[i][4] + bv, acc[i][5] + bv, acc[i][6] + bv, acc[i][7] + bv);
  }
}

// ---------------- GLU + residual + LN, in-place u update + stash save ----------------
__global__ __launch_bounds__(256) void k_glu_ln(const float* __restrict__ z,
                                                float* __restrict__ u,
                                                float* __restrict__ stash,
                                                const float* __restrict__ lng,
                                                const float* __restrict__ lnb,
                                                int c) {
  __shared__ float zs[256][33];
  __shared__ float usm[128][33];
  int lblk = blockIdx.x, b = blockIdx.y;
  int lc0 = lblk * 32;
  long long l0g = (long long)c * CH_ + lc0;
  for (int i = threadIdx.x; i < 256 * 32; i += 256) {
    int p = i >> 5, l = i & 31;
    zs[p][l] = z[(long long)(b * 256 + p) * CH_ + lc0 + l];
  }
  for (int i = threadIdx.x; i < 128 * 32; i += 256) {
    int hh = i >> 5, l = i & 31;
    usm[hh][l] = u[(long long)(b * H_ + hh) * L_ + l0g + l];
  }
  __syncthreads();
  if (lc0 >= CH_ - LMAX_ && c < NCH_ - 1) {
    int so = lc0 - (CH_ - LMAX_);
    for (int i = threadIdx.x; i < 128 * 32; i += 256) {
      int hh = i >> 5, l = i & 31;
      stash[(b * H_ + hh) * LMAX_ + so + l] = usm[hh][l];
    }
  }
  __syncthreads();
  int lane = threadIdx.x & 63, w = threadIdx.x >> 6;
  float g0 = lng[lane], g1 = lng[lane + 64];
  float bb0 = lnb[lane], bb1 = lnb[lane + 64];
  for (int l = w * 8; l < w * 8 + 8; l++) {
    float a0 = zs[lane][l], a1 = zs[lane + 64][l];
    float s0 = zs[lane + 128][l], s1 = zs[lane + 192][l];
    float v0 = a0 * (1.f / (1.f + expf(-s0))) + usm[lane][l];
    float v1 = a1 * (1.f / (1.f + expf(-s1))) + usm[lane + 64][l];
    float sum = v0 + v1, sq = v0 * v0 + v1 * v1;
    #pragma unroll
    for (int mm = 1; mm < 64; mm <<= 1) {
      sum += __shfl_xor(sum, mm);
      sq += __shfl_xor(sq, mm);
    }
    float mean = sum * (1.f / 128.f);
    float var = sq * (1.f / 128.f) - mean * mean;
    float rstd = rsqrtf(var + 1e-5f);
    usm[lane][l] = (v0 - mean) * rstd * g0 + bb0;
    usm[lane + 64][l] = (v1 - mean) * rstd * g1 + bb1;
  }
  __syncthreads();
  for (int i = threadIdx.x; i < 128 * 32; i += 256) {
    int hh = i >> 5, l = i & 31;
    u[(long long)(b * H_ + hh) * L_ + l0g + l] = usm[hh][l];
  }
}

// ---------------- mean pool ----------------
__global__ __launch_bounds__(256) void k_pool(const float* __restrict__ u,
                                              float* __restrict__ feat) {
  int bh = blockIdx.x;
  const float4* p = (const float4*)(u + (long long)bh * L_);
  float s = 0.f;
  for (int i = threadIdx.x; i < L_ / 4; i += 256) {
    float4 v = p[i];
    s += v.x + v.y + v.z + v.w;
  }
  __shared__ float smv[256];
  smv[threadIdx.x] = s;
  __syncthreads();
  for (int st = 128; st > 0; st >>= 1) {
    if (threadIdx.x < st) smv[threadIdx.x] += smv[threadIdx.x + st];
    __syncthreads();
  }
  if (threadIdx.x == 0) feat[bh] = smv[0] * (1.f / L_);
}

// ---------------- decoder ----------------
__global__ __launch_bounds__(256) void k_dec(const float* __restrict__ feat,
                                             const float* __restrict__ dw,
                                             const float* __restrict__ db,
                                             float* __restrict__ rep) {
  int idx = blockIdx.x * 256 + threadIdx.x;
  if (idx >= B_ * REP_) return;
  int b = idx / REP_, r = idx - b * REP_;
  float s = db[r];
  #pragma unroll 8
  for (int h = 0; h < H_; h++) s = fmaf(feat[b * H_ + h], dw[h * REP_ + r], s);
  rep[idx] = s;
}

// ---------------- heads ----------------
__global__ __launch_bounds__(256) void k_head(const float* __restrict__ rep,
                                              const float* __restrict__ hw,
                                              const float* __restrict__ hb,
                                              float* __restrict__ out) {
  int idx = blockIdx.x * 256 + threadIdx.x;
  if (idx >= 4 * B_ * TS_ * CLS_) return;
  int c = idx % CLS_;
  int t = (idx / CLS_) % TS_;
  int b = (idx / (CLS_ * TS_)) % B_;
  int k = idx / (CLS_ * TS_ * B_);
  float s = hb[k * CLS_ + c];
  const float* rp = rep + ((long long)b * TS_ + t) * MR_;
  #pragma unroll
  for (int m = 0; m < MR_; m++) s = fmaf(rp[m], hw[(k * MR_ + m) * CLS_ + c], s);
  out[idx] = s;
}

extern "C" void kernel_launch(void* const* d_in, const int* in_sizes, int n_in,
                              void* d_out, int out_size, void* d_ws, size_t ws_size,
                              hipStream_t stream) {
  const float* x = (const float*)d_in[0];
  const float* enc_w = (const float*)d_in[1];
  const float* enc_b = (const float*)d_in[2];
  const float* log_dt = (const float*)d_in[3];
  const float* log_A_real = (const float*)d_in[4];
  const float* A_imag = (const float*)d_in[5];
  const float* C_re = (const float*)d_in[6];
  const float* C_im = (const float*)d_in[7];
  const float* Dv = (const float*)d_in[8];
  const float* out_w = (const float*)d_in[9];
  const float* out_b = (const float*)d_in[10];
  const float* ln_g = (const float*)d_in[11];
  const float* ln_b = (const float*)d_in[12];
  const float* dec_w = (const float*)d_in[13];
  const float* dec_b = (const float*)d_in[14];
  const float* head_w = (const float*)d_in[15];
  const float* head_b = (const float*)d_in[16];

  // Workspace (floats): u 40.96M | y 2.048M slots (bf16 chunk) | z 8.192M |
  //   stash 262144 | Ke 393216 slots (bf16) | ct 131072 | feat 256 | rep 32032
  // total ~208.1 MB
  if (ws_size < 210000000ULL) return;

  float* ws = (float*)d_ws;
  float* u = ws;
  ushort_t* y = (ushort_t*)(ws + 40960000);
  float* z = ws + 40960000 + 2048000;
  float* stash = z + 8192000;
  ushort_t* Ke = (ushort_t*)(stash + 262144);
  float* ct = (float*)(Ke + NL_ * H_ * KE_STRIDE_);
  float* feat = ct + 131072;
  float* rep = feat + 256;

  k_encode<<<(B_ * H_ * L_ / 4 + 255) / 256, 256, 0, stream>>>(x, enc_w, enc_b, u);
  k_ct<<<(NL_ * H_ * N_ + 255) / 256, 256, 0, stream>>>(log_dt, log_A_real, A_imag,
                                                        C_re, C_im, ct);
  k_ke<<<NL_ * H_, 256, 0, stream>>>(ct, Ke);

  for (int i = 0; i < NL_; i++) {
    for (int c = 0; c < NCH_; c++) {
      k_conv_mfma<<<B_ * H_ * 8, 256, 0, stream>>>(u, stash, Ke, Dv, y, i, c);
      k_gemm<<<dim3(CH_ / 128, 2, B_), 256, 0, stream>>>(
          y, out_w + i * 256 * 128, out_b + i * 256, z);
      k_glu_ln<<<dim3(CH_ / 32, B_), 256, 0, stream>>>(z, u, stash, ln_g + i * H_,
                                                       ln_b + i * H_, c);
    }
  }
  k_pool<<<B_ * H_, 256, 0, stream>>>(u, feat);
  k_dec<<<(B_ * REP_ + 255) / 256, 256, 0, stream>>>(feat, dec_w, dec_b, rep);
  k_head<<<(4 * B_ * TS_ * CLS_ + 255) / 256, 256, 0, stream>>>(rep, head_w, head_b,
                                                               (float*)d_out);
}

// Round 5
// 2494.913 us; speedup vs baseline: 2.9565x; 1.5368x over previous
//
#include <hip/hip_runtime.h>
#include <math.h>

#define B_ 2
#define L_ 160000
#define H_ 128
#define N_ 64
#define NL_ 4
#define LMAX_ 1024
#define TS_ 1001
#define MR_ 16
#define CLS_ 88
#define REP_ 16016

#define CH_ 16000             // l-chunk (10 chunks per layer)
#define NCH_ 10
#define NJ_ 40                // conv tap blocks per tile
#define WIN_ 3208             // reversed-window elements per phase copy
#define OUTB_ 2048            // outputs per conv block
#define KE_STRIDE_ 1536       // Ke entries per (layer,h): d in [-256, 1280)

typedef unsigned short ushort_t;
typedef unsigned int uint_t;
typedef short bf16x8 __attribute__((ext_vector_type(8)));
typedef float f32x4 __attribute__((ext_vector_type(4)));

__device__ __forceinline__ float bf2f(ushort_t h) {
  uint_t u = ((uint_t)h) << 16;
  return __uint_as_float(u);
}
__device__ __forceinline__ ushort_t f2bf(float f) {
  uint_t u = __float_as_uint(f);
  uint_t r = (u + 0x7fffu + ((u >> 16) & 1u)) >> 16;
  return (ushort_t)r;
}

// ---------------- encoder ----------------
__global__ __launch_bounds__(256) void k_encode(const float* __restrict__ x,
                                                const float* __restrict__ enc_w,
                                                const float* __restrict__ enc_b,
                                                float* __restrict__ u) {
  int idx = blockIdx.x * 256 + threadIdx.x;
  int idx4 = idx * 4;
  int b = idx4 / (H_ * L_);
  int rem = idx4 - b * (H_ * L_);
  int h = rem / L_;
  int l = rem - h * L_;
  float w = enc_w[h], bb = enc_b[h];
  float4 xv = *(const float4*)(x + b * L_ + l);
  float4 o = make_float4(xv.x * w + bb, xv.y * w + bb, xv.z * w + bb, xv.w * w + bb);
  *(float4*)(u + (long long)(b * H_ + h) * L_ + l) = o;
}

// ---------------- discretization ----------------
__global__ __launch_bounds__(256) void k_ct(const float* __restrict__ log_dt,
                                            const float* __restrict__ log_A_real,
                                            const float* __restrict__ A_imag,
                                            const float* __restrict__ C_re,
                                            const float* __restrict__ C_im,
                                            float* __restrict__ ct) {
  int idx = blockIdx.x * 256 + threadIdx.x;
  if (idx >= NL_ * H_ * N_) return;
  int h = (idx / N_) % H_;
  int i = idx / (N_ * H_);
  float dt = expf(log_dt[i * H_ + h]);
  float are = -expf(log_A_real[idx]);
  float aim = A_imag[idx];
  float dr = are * dt, di = aim * dt;
  float e = expf(dr);
  float si, co;
  sincosf(di, &si, &co);
  float er = e * co - 1.0f;
  float ei = e * si;
  float den = are * are + aim * aim;
  float qr = (er * are + ei * aim) / den;
  float qi = (ei * are - er * aim) / den;
  float cr = C_re[idx], cim = C_im[idx];
  ct[idx * 4 + 0] = dr;
  ct[idx * 4 + 1] = di;
  ct[idx * 4 + 2] = cr * qr - cim * qi;
  ct[idx * 4 + 3] = cr * qi + cim * qr;
}

// ---------------- Ke[layer,h, s] bf16 (4-way split over s) ----------------
__global__ __launch_bounds__(256) void k_ke(const float* __restrict__ ct,
                                            ushort_t* __restrict__ Ke) {
  int q = blockIdx.x & 3;
  int ih = blockIdx.x >> 2;
  __shared__ float4 cs[N_];
  if (threadIdx.x < N_) cs[threadIdx.x] = ((const float4*)ct)[ih * N_ + threadIdx.x];
  __syncthreads();
  int s0 = q * (KE_STRIDE_ / 4);
  for (int s = s0 + threadIdx.x; s < s0 + KE_STRIDE_ / 4; s += 256) {
    int d = s - 256;
    float val = 0.f;
    if (d >= 0 && d < LMAX_) {
      float fl = (float)d;
      float acc = 0.f;
      #pragma unroll 4
      for (int n = 0; n < N_; n++) {
        float4 qv = cs[n];
        float e = expf(qv.x * fl);
        float si, co;
        sincosf(qv.y * fl, &si, &co);
        acc += e * (qv.z * co - qv.w * si);
      }
      val = 2.f * acc;
    }
    Ke[(size_t)ih * KE_STRIDE_ + s] = f2bf(val);
  }
}

// ---------------- W -> bf16 ----------------
__global__ __launch_bounds__(256) void k_wprep(const float* __restrict__ W,
                                               ushort_t* __restrict__ Wb) {
  int idx = blockIdx.x * 256 + threadIdx.x;   // NL*256*128 = 131072
  Wb[idx] = f2bf(W[idx]);
}

// ---------------- MFMA conv + skip + GELU -> bf16 y (chunk-local) ----------------
__global__ __launch_bounds__(256) void k_conv_mfma(const float* __restrict__ u,
                                                   const float* __restrict__ stash,
                                                   const ushort_t* __restrict__ Ke,
                                                   const float* __restrict__ Dv,
                                                   ushort_t* __restrict__ y,
                                                   int layer, int c) {
  int sub = blockIdx.x & 7;
  int bh = blockIdx.x >> 3;
  int h = bh & (H_ - 1);
  int O0 = sub * OUTB_;
  int Gmax = O0 + 2063;
  __shared__ ushort_t win[4 * WIN_];
  int tid = threadIdx.x;
  int lane = tid & 63, w = tid >> 6;
  int m = lane & 15, g = lane >> 4;

  const ushort_t* keh = Ke + (size_t)(layer * H_ + h) * KE_STRIDE_ + 256;
  bf16x8 Kf[NJ_];
  #pragma unroll
  for (int jjj = 0; jjj < NJ_; jjj++) {
    Kf[jjj] = *(const bf16x8*)(keh + 16 * m + 8 * g + 32 * jjj - 256);
  }

  const float* ubh = u + (size_t)bh * L_;
  const float* sbh = stash + bh * LMAX_;
  for (int T = tid; T < WIN_ / 8; T += 256) {
    int topt = Gmax - 8 * T;
    ushort_t vb[16];
    if (topt - 15 >= 0 && (long long)c * CH_ + topt < L_) {
      const float4* fp = (const float4*)(ubh + (long long)c * CH_ + topt - 15);
      float4 q0 = fp[0], q1 = fp[1], q2 = fp[2], q3 = fp[3];
      float tmp[16] = {q0.x, q0.y, q0.z, q0.w, q1.x, q1.y, q1.z, q1.w,
                       q2.x, q2.y, q2.z, q2.w, q3.x, q3.y, q3.z, q3.w};
      #pragma unroll
      for (int d = 0; d < 16; d++) vb[d] = f2bf(tmp[15 - d]);
    } else {
      #pragma unroll
      for (int d = 0; d < 16; d++) {
        int gl = topt - d;
        float v = 0.f;
        if (gl >= 0) {
          long long gg = (long long)c * CH_ + gl;
          if (gg < L_) v = ubh[gg];
        } else if (gl >= -LMAX_ && c > 0) {
          v = sbh[LMAX_ + gl];
        }
        vb[d] = f2bf(v);
      }
    }
    #pragma unroll
    for (int p = 0; p < 4; p++) {
      union { bf16x8 v; ushort_t s[8]; } gr;
      #pragma unroll
      for (int e = 0; e < 8; e++) gr.s[e] = vb[p + e];
      *(bf16x8*)((char*)win + p * (2 * WIN_) + 16 * T) = gr.v;
    }
  }
  __syncthreads();

  const char* wb = (const char*)win;
  int l0A = O0 + (w << 9);
  f32x4 accA = {0.f, 0.f, 0.f, 0.f}, accB = {0.f, 0.f, 0.f, 0.f};
  int t0 = Gmax - l0A - m + 8 * g - 256;
  #pragma unroll
  for (int jjj = 0; jjj < NJ_; jjj++) {
    int tA = t0 + (jjj << 5);
    int pA = tA & 3;
    const char* baseA = wb + pA * (2 * WIN_) + 2 * (tA - pA);
    union { bf16x8 v; short4 h[2]; } fa, fb;
    fa.h[0] = *(const short4*)baseA;
    fa.h[1] = *(const short4*)(baseA + 8);
    accA = __builtin_amdgcn_mfma_f32_16x16x32_bf16(fa.v, Kf[jjj], accA, 0, 0, 0);
    const char* baseB = baseA - 512;
    fb.h[0] = *(const short4*)baseB;
    fb.h[1] = *(const short4*)(baseB + 8);
    accB = __builtin_amdgcn_mfma_f32_16x16x32_bf16(fb.v, Kf[jjj], accB, 0, 0, 0);
  }

  float Dh = Dv[layer * H_ + h];
  ushort_t* ybh = y + (size_t)bh * CH_;
  #pragma unroll
  for (int tile = 0; tile < 2; tile++) {
    f32x4 acc = tile ? accB : accA;
    int l0 = l0A + tile * 256;
    int outb = l0 + 16 * m + 4 * g;
    int tu = Gmax - outb - 3;
    int pu = tu & 3;
    union { short4 s4; ushort_t us[4]; } uu;
    uu.s4 = *(const short4*)(wb + pu * (2 * WIN_) + 2 * (tu - pu));
    union { ushort_t s[4]; short4 v; } pk;
    #pragma unroll
    for (int r = 0; r < 4; r++) {
      float uval = bf2f(uu.us[3 - r]);
      float v = acc[r] + Dh * uval;
      float t = tanhf(0.7978845608028654f * (v + 0.044715f * v * v * v));
      pk.s[r] = f2bf(0.5f * v * (1.f + t));
    }
    if (outb < CH_) *(short4*)(ybh + outb) = pk.v;
  }
}

// ---------------- fused MFMA GEMM + bias + GLU + residual + LN ----------------
// Block: 256p x 64l, 4 waves. Wave w: p in [32w,32w+32) u [128+32w,128+32w+32).
// yT LDS: [l][k] bf16 with octet swizzle kb' = kb ^ (l>>3).
__global__ __launch_bounds__(256) void k_fused(const ushort_t* __restrict__ y,
                                               const ushort_t* __restrict__ Wb,
                                               const float* __restrict__ ob,
                                               float* __restrict__ u,
                                               float* __restrict__ stash,
                                               const float* __restrict__ lng,
                                               const float* __restrict__ lnb,
                                               int c) {
  __shared__ ushort_t yT[64 * 136];        // 17408 B
  __shared__ float vs[128 * 66];           // 33792 B
  __shared__ float redS[4 * 64];
  __shared__ float redQ[4 * 64];
  int lblk = blockIdx.x, b = blockIdx.y;
  int lc0 = lblk * 64;
  int tid = threadIdx.x;
  int lane = tid & 63, w = tid >> 6;
  int m = lane & 15, g = lane >> 4;

  // ---- W fragments (A operand): 16 frags, preloaded ----
  bf16x8 Wf[4][4];   // [pi][ks]
  #pragma unroll
  for (int pi = 0; pi < 4; pi++) {
    int pbase = (pi < 2) ? (32 * w + 16 * pi) : (96 + 32 * w + 16 * pi);
    const ushort_t* wrow = Wb + (pbase + m) * 128;
    #pragma unroll
    for (int ks = 0; ks < 4; ks++)
      Wf[pi][ks] = *(const bf16x8*)(wrow + 32 * ks + 8 * g);
  }

  // ---- stage yT with transpose+swizzle ----
  {
    int s = tid & 7;
    int kkb = tid >> 3;                     // 32 k-rows per pass
    #pragma unroll
    for (int p = 0; p < 4; p++) {
      int kk = kkb + 32 * p;
      const ushort_t* yp = y + ((size_t)b * H_ + kk) * CH_ + lc0 + 8 * s;
      uint4 vv = *(const uint4*)yp;
      const ushort_t* hp = (const ushort_t*)&vv;
      int sw = 8 * ((kk >> 3) ^ s) + (kk & 7);
      #pragma unroll
      for (int e = 0; e < 8; e++)
        yT[(8 * s + e) * 136 + sw] = hp[e];
    }
  }
  __syncthreads();

  // ---- MFMA: 64 per wave ----
  f32x4 acc[4][4];   // [pi][lj]
  #pragma unroll
  for (int pi = 0; pi < 4; pi++)
    #pragma unroll
    for (int lj = 0; lj < 4; lj++) acc[pi][lj] = (f32x4){0.f, 0.f, 0.f, 0.f};
  #pragma unroll
  for (int ks = 0; ks < 4; ks++) {
    bf16x8 yf[4];
    #pragma unroll
    for (int lj = 0; lj < 4; lj++) {
      int l = 16 * lj + m;
      yf[lj] = *(const bf16x8*)(yT + l * 136 + 8 * ((4 * ks + g) ^ (l >> 3)));
    }
    #pragma unroll
    for (int pi = 0; pi < 4; pi++)
      #pragma unroll
      for (int lj = 0; lj < 4; lj++)
        acc[pi][lj] = __builtin_amdgcn_mfma_f32_16x16x32_bf16(Wf[pi][ks], yf[lj],
                                                              acc[pi][lj], 0, 0, 0);
  }

  // ---- epilogue: bias + GLU + residual (in-register), v -> LDS ----
  long long l0g = (long long)c * CH_ + lc0;
  bool tail = (lc0 >= CH_ - LMAX_) && (c < NCH_ - 1);
  #pragma unroll
  for (int pi = 0; pi < 2; pi++) {
    int pbA = 32 * w + 16 * pi;
    #pragma unroll
    for (int lj = 0; lj < 4; lj++) {
      int gcol = lc0 + 16 * lj + m;
      #pragma unroll
      for (int r = 0; r < 4; r++) {
        int pa = pbA + 4 * g + r;
        float a = acc[pi][lj][r] + ob[pa];
        float sv = acc[pi + 2][lj][r] + ob[pa + 128];
        float uo = u[(size_t)(b * H_ + pa) * L_ + (long long)c * CH_ + gcol];
        float v = a * (1.f / (1.f + expf(-sv))) + uo;
        vs[pa * 66 + 16 * lj + m] = v;
        if (tail) stash[(b * H_ + pa) * LMAX_ + gcol - (CH_ - LMAX_)] = uo;
      }
    }
  }
  __syncthreads();

  // ---- LayerNorm over H, write u ----
  int lq = tid & 63, q = tid >> 6;
  float sum = 0.f, sq = 0.f;
  #pragma unroll 8
  for (int hh = 32 * q; hh < 32 * q + 32; hh++) {
    float v = vs[hh * 66 + lq];
    sum += v;
    sq += v * v;
  }
  redS[q * 64 + lq] = sum;
  redQ[q * 64 + lq] = sq;
  __syncthreads();
  sum = redS[lq] + redS[64 + lq] + redS[128 + lq] + redS[192 + lq];
  sq = redQ[lq] + redQ[64 + lq] + redQ[128 + lq] + redQ[192 + lq];
  float mean = sum * (1.f / 128.f);
  float var = sq * (1.f / 128.f) - mean * mean;
  float rstd = rsqrtf(var + 1e-5f);
  #pragma unroll 8
  for (int hh = 32 * q; hh < 32 * q + 32; hh++) {
    float val = (vs[hh * 66 + lq] - mean) * rstd * lng[hh] + lnb[hh];
    u[(size_t)(b * H_ + hh) * L_ + l0g + lq] = val;
  }
}

// ---------------- mean pool ----------------
__global__ __launch_bounds__(256) void k_pool(const float* __restrict__ u,
                                              float* __restrict__ feat) {
  int bh = blockIdx.x;
  const float4* p = (const float4*)(u + (long long)bh * L_);
  float s = 0.f;
  for (int i = threadIdx.x; i < L_ / 4; i += 256) {
    float4 v = p[i];
    s += v.x + v.y + v.z + v.w;
  }
  __shared__ float smv[256];
  smv[threadIdx.x] = s;
  __syncthreads();
  for (int st = 128; st > 0; st >>= 1) {
    if (threadIdx.x < st) smv[threadIdx.x] += smv[threadIdx.x + st];
    __syncthreads();
  }
  if (threadIdx.x == 0) feat[bh] = smv[0] * (1.f / L_);
}

// ---------------- decoder ----------------
__global__ __launch_bounds__(256) void k_dec(const float* __restrict__ feat,
                                             const float* __restrict__ dw,
                                             const float* __restrict__ db,
                                             float* __restrict__ rep) {
  int idx = blockIdx.x * 256 + threadIdx.x;
  if (idx >= B_ * REP_) return;
  int b = idx / REP_, r = idx - b * REP_;
  float s = db[r];
  #pragma unroll 8
  for (int h = 0; h < H_; h++) s = fmaf(feat[b * H_ + h], dw[h * REP_ + r], s);
  rep[idx] = s;
}

// ---------------- heads ----------------
__global__ __launch_bounds__(256) void k_head(const float* __restrict__ rep,
                                              const float* __restrict__ hw,
                                              const float* __restrict__ hb,
                                              float* __restrict__ out) {
  int idx = blockIdx.x * 256 + threadIdx.x;
  if (idx >= 4 * B_ * TS_ * CLS_) return;
  int c = idx % CLS_;
  int t = (idx / CLS_) % TS_;
  int b = (idx / (CLS_ * TS_)) % B_;
  int k = idx / (CLS_ * TS_ * B_);
  float s = hb[k * CLS_ + c];
  const float* rp = rep + ((long long)b * TS_ + t) * MR_;
  #pragma unroll
  for (int m = 0; m < MR_; m++) s = fmaf(rp[m], hw[(k * MR_ + m) * CLS_ + c], s);
  out[idx] = s;
}

extern "C" void kernel_launch(void* const* d_in, const int* in_sizes, int n_in,
                              void* d_out, int out_size, void* d_ws, size_t ws_size,
                              hipStream_t stream) {
  const float* x = (const float*)d_in[0];
  const float* enc_w = (const float*)d_in[1];
  const float* enc_b = (const float*)d_in[2];
  const float* log_dt = (const float*)d_in[3];
  const float* log_A_real = (const float*)d_in[4];
  const float* A_imag = (const float*)d_in[5];
  const float* C_re = (const float*)d_in[6];
  const float* C_im = (const float*)d_in[7];
  const float* Dv = (const float*)d_in[8];
  const float* out_w = (const float*)d_in[9];
  const float* out_b = (const float*)d_in[10];
  const float* ln_g = (const float*)d_in[11];
  const float* ln_b = (const float*)d_in[12];
  const float* dec_w = (const float*)d_in[13];
  const float* dec_b = (const float*)d_in[14];
  const float* head_w = (const float*)d_in[15];
  const float* head_b = (const float*)d_in[16];

  // Workspace (f32 slots): u 40.96M | y 2.048M | stash 262144 | Ke 393216 |
  //   ct 131072 | Wb 65536 | feat 256 | rep 32032  => ~175.6 MB
  if (ws_size < 176000000ULL) return;

  float* ws = (float*)d_ws;
  float* u = ws;
  ushort_t* y = (ushort_t*)(ws + 40960000);
  float* stash = ws + 40960000 + 2048000;
  ushort_t* Ke = (ushort_t*)(stash + 262144);
  float* ct = stash + 262144 + 393216;
  ushort_t* Wb = (ushort_t*)(ct + 131072);
  float* feat = ct + 131072 + 65536;
  float* rep = feat + 256;

  k_encode<<<(B_ * H_ * L_ / 4 + 255) / 256, 256, 0, stream>>>(x, enc_w, enc_b, u);
  k_ct<<<(NL_ * H_ * N_ + 255) / 256, 256, 0, stream>>>(log_dt, log_A_real, A_imag,
                                                        C_re, C_im, ct);
  k_ke<<<NL_ * H_ * 4, 256, 0, stream>>>(ct, Ke);
  k_wprep<<<NL_ * 256 * 128 / 256, 256, 0, stream>>>(out_w, Wb);

  for (int i = 0; i < NL_; i++) {
    for (int c = 0; c < NCH_; c++) {
      k_conv_mfma<<<B_ * H_ * 8, 256, 0, stream>>>(u, stash, Ke, Dv, y, i, c);
      k_fused<<<dim3(CH_ / 64, B_), 256, 0, stream>>>(
          y, Wb + (size_t)i * 256 * 128, out_b + i * 256, u, stash,
          ln_g + i * H_, ln_b + i * H_, c);
    }
  }
  k_pool<<<B_ * H_, 256, 0, stream>>>(u, feat);
  k_dec<<<(B_ * REP_ + 255) / 256, 256, 0, stream>>>(feat, dec_w, dec_b, rep);
  k_head<<<(4 * B_ * TS_ * CLS_ + 255) / 256, 256, 0, stream>>>(rep, head_w, head_b,
                                                               (float*)d_out);
}